// Round 19
// baseline (172.841 us; speedup 1.0000x reference)
//
#include <hip/hip_runtime.h>
#include <hip/hip_fp16.h>
#include <math.h>

#define SELU_LAMBDA 1.0507009873554805f
#define SELU_ALPHA  1.6732632423543772f

#define BSHIFT 9
#define BNODES 512          // nodes per bucket
#define CAP    10240        // bucket capacity (mean 8192, +22 sigma)
#define CHUNK  4096         // edges per k_bin block
#define NSLOT  64           // stats atomic spreading slots
#define HOPBLKS 2048        // persistent hop blocks (8/CU -> 32 waves/CU)

typedef _Float16 half8 __attribute__((ext_vector_type(8)));
typedef float f32x4 __attribute__((ext_vector_type(4)));

// fp16 helpers
__device__ __forceinline__ unsigned int f2h2(float a, float b) {
  __half2 h = __floats2half2_rn(a, b);
  return *(unsigned int*)&h;
}
__device__ __forceinline__ float2 h22f2(unsigned int u) {
  __half2 h = *(__half2*)&u;
  return __half22float2(h);
}
__device__ __forceinline__ unsigned int hadd2(unsigned int a, unsigned int b) {
  __half2 x = *(__half2*)&a, y = *(__half2*)&b;
  __half2 r = __hadd2(x, y);
  return *(unsigned int*)&r;
}

// ---------------------------------------------------------------- setup: zero cursor/stats/pads + W1/W2 MFMA-fragment prep
__global__ __launch_bounds__(256) void k_setup(int* __restrict__ cursor,
    float* __restrict__ stats, unsigned short* __restrict__ h1pad,
    unsigned short* __restrict__ h2pad, unsigned short* __restrict__ ybpad,
    const float* __restrict__ W1, unsigned short* __restrict__ Wfrag,
    const float* __restrict__ W2, unsigned short* __restrict__ W2frag) {
  int i = blockIdx.x * 256 + threadIdx.x;
  if (i < 256) cursor[i] = 0;
  if (i < NSLOT * 128) stats[i] = 0.f;
  if (i < 64) { h1pad[i] = 0; h2pad[i] = 0; }
  if (i < 16) ybpad[i] = 0;
  if (i < 1024) {  // Wfrag[(ntile*4+kb)*64+lane][8]: W1[k0+j][ntile*16+(lane&15)]
    int lane = i & 63;
    int kb = (i >> 6) & 3;
    int ntile = i >> 8;
    int k0 = kb * 32 + (lane >> 4) * 8;
    int col = ntile * 16 + (lane & 15);
    unsigned short tmp[8];
#pragma unroll
    for (int j = 0; j < 8; ++j) {
      __half h = __float2half_rn(W1[(size_t)(k0 + j) * 64 + col]);
      tmp[j] = *(unsigned short*)&h;
    }
    *(uint4*)&Wfrag[(size_t)i * 8] = *(uint4*)tmp;
  }
  if (i < 128) {   // W2frag[kb*64+lane][8]: W2[k0+j][lane&15]
    int lane = i & 63;
    int kb = i >> 6;
    int k0 = kb * 32 + (lane >> 4) * 8;
    int col = lane & 15;
    unsigned short tmp[8];
#pragma unroll
    for (int j = 0; j < 8; ++j) {
      __half h = __float2half_rn(W2[(size_t)(k0 + j) * 16 + col]);
      tmp[j] = *(unsigned short*)&h;
    }
    *(uint4*)&W2frag[(size_t)i * 8] = *(uint4*)tmp;
  }
}

// ---------------------------------------------------------------- fused: bin edges (blocks < nbin) + MFMA GEMM1 (rest)
__global__ __launch_bounds__(256) void k_bin_gemm1(const int* __restrict__ src,
    const int* __restrict__ dst, int* __restrict__ cursor,
    int* __restrict__ binned, int e, int nbin,
    const float* __restrict__ A, const unsigned short* __restrict__ Wfrag,
    unsigned short* __restrict__ H, int n) {
  if ((int)blockIdx.x < nbin) {
    __shared__ int hist[256];
    __shared__ int gb[256];
    const int tid = threadIdx.x;
    hist[tid] = 0;
    __syncthreads();
    const int base = blockIdx.x * CHUNK;
    int bk[16], rk[16], pk[16];
#pragma unroll
    for (int k = 0; k < 16; ++k) {
      int i = base + k * 256 + tid;
      if (i < e) {
        int d = dst[i];
        int s = src[i];
        int b = d >> BSHIFT;
        bk[k] = b;
        pk[k] = s | ((d & (BNODES - 1)) << 17);
        rk[k] = atomicAdd(&hist[b], 1);
      } else {
        bk[k] = -1;
      }
    }
    __syncthreads();
    int h = hist[tid];
    if (h > 0) gb[tid] = atomicAdd(&cursor[tid], h);
    __syncthreads();
#pragma unroll
    for (int k = 0; k < 16; ++k) {
      if (bk[k] >= 0) binned[bk[k] * CAP + gb[bk[k]] + rk[k]] = pk[k];
    }
    return;
  }
  // ---- gemm1 part
  const int gblk = blockIdx.x - nbin;
  const int lane = threadIdx.x & 63;
  const int wv = threadIdx.x >> 6;
  const int r0 = gblk * 64 + wv * 16;

  const int brow = r0 + (lane & 15);
  const int browc = brow < n ? brow : n - 1;
  const float* xrow = A + (size_t)browc * 128 + (lane >> 4) * 8;

  f32x4 acc[4] = {};
#pragma unroll
  for (int kb = 0; kb < 4; ++kb) {
    float4 p = *(const float4*)(xrow + kb * 32);
    float4 q = *(const float4*)(xrow + kb * 32 + 4);
    half8 xf;
    xf[0] = (_Float16)p.x; xf[1] = (_Float16)p.y;
    xf[2] = (_Float16)p.z; xf[3] = (_Float16)p.w;
    xf[4] = (_Float16)q.x; xf[5] = (_Float16)q.y;
    xf[6] = (_Float16)q.z; xf[7] = (_Float16)q.w;
#pragma unroll
    for (int nt = 0; nt < 4; ++nt) {
      half8 wf = *(const half8*)&Wfrag[(size_t)((nt * 4 + kb) * 64 + lane) * 8];
      acc[nt] = __builtin_amdgcn_mfma_f32_16x16x32_f16(wf, xf, acc[nt], 0, 0, 0);
    }
  }
  const int orow = r0 + (lane & 15);
  if (orow < n) {
#pragma unroll
    for (int nt = 0; nt < 4; ++nt) {
      int col = nt * 16 + (lane >> 4) * 4;
      uint2 o;
      o.x = f2h2(acc[nt][0], acc[nt][1]);
      o.y = f2h2(acc[nt][2], acc[nt][3]);
      *(uint2*)&H[(size_t)orow * 64 + col] = o;
    }
  }
}

// ---------------------------------------------------------------- phase 2: per-bucket CSR build (512 threads)
__global__ __launch_bounds__(512) void k_build(const int* __restrict__ binned,
    const int* __restrict__ cursor, int* __restrict__ offs,
    int* __restrict__ csr, int n, int nb, int etot) {
  __shared__ int sc[2][256];
  __shared__ int deg[BNODES];
  __shared__ int pre[BNODES];
  __shared__ int wsum[8];
  __shared__ int stage[CAP];
  __shared__ int s_cbase;
  const int b = blockIdx.x;
  const int tid = threadIdx.x;

  // replicated inclusive scan of the nb bucket counts (first 256 threads)
  if (tid < 256) sc[0][tid] = (tid < nb) ? cursor[tid] : 0;
  __syncthreads();
  int cur = 0;
  for (int d = 1; d < 256; d <<= 1) {
    if (tid < 256) {
      int t = sc[cur][tid];
      if (tid >= d) t += sc[cur][tid - d];
      sc[cur ^ 1][tid] = t;
    }
    cur ^= 1;
    __syncthreads();
  }
  if (tid == 0) {
    s_cbase = (b == 0) ? 0 : sc[cur][b - 1];
    if (b == 0) offs[n] = etot;
  }
  deg[tid] = 0;
  __syncthreads();
  const int cbase = s_cbase;
  const int cnt = sc[cur][b] - cbase;

  const int nodeBase = b << BSHIFT;
  const int* gsrc = binned + b * CAP;

  for (int i = tid; i < cnt; i += 512) atomicAdd(&deg[gsrc[i] >> 17], 1);
  __syncthreads();

  // exclusive scan of deg[512]: 1 element/thread (8 waves)
  const int lane = tid & 63, w = tid >> 6;
  int a0 = deg[tid];
  int s = a0;
#pragma unroll
  for (int d = 1; d < 64; d <<= 1) {
    int t = __shfl_up(s, d, 64);
    if (lane >= d) s += t;
  }
  if (lane == 63) wsum[w] = s;
  __syncthreads();
  if (tid == 0) {
    int acc = 0;
#pragma unroll
    for (int j = 0; j < 8; ++j) { int t = wsum[j]; wsum[j] = acc; acc += t; }
  }
  __syncthreads();
  pre[tid] = wsum[w] + s - a0;
  deg[tid] = 0;   // reset for use as cursor
  __syncthreads();

  const int nNodes = min(BNODES, n - nodeBase);
  for (int i = tid; i < nNodes; i += 512) offs[nodeBase + i] = cbase + pre[i];

  for (int i = tid; i < cnt; i += 512) {
    int v = gsrc[i];
    int dl = v >> 17;
    int p = pre[dl] + atomicAdd(&deg[dl], 1);
    stage[p] = v & 0x1FFFF;
  }
  __syncthreads();
  for (int i = tid; i < cnt; i += 512) csr[cbase + i] = stage[i];
}

// ---------------------------------------------------------------- hop at D=64 (fp16 in/out), persistent grid-stride
// wave = one node per iteration; 4 sub-groups of 16 lanes; lane loads 4 dims (8B).
// All 32 edge indices preloaded (pad = zero row n); tail for deg > 32.
__device__ __forceinline__ void hop64_gather32(const unsigned short* __restrict__ hin,
    const int* __restrict__ csr, int beg, int end, int sub, int t, int npad,
    unsigned int& a01, unsigned int& a23) {
  a01 = 0u; a23 = 0u;
  int idx[8];
#pragma unroll
  for (int k = 0; k < 8; ++k) {
    int a = beg + k * 4 + sub;
    idx[k] = (a < end) ? csr[a] : npad;
  }
  uint2 v[8];
#pragma unroll
  for (int k = 0; k < 8; ++k)
    v[k] = *(const uint2*)&hin[(size_t)idx[k] * 64 + 4 * t];
#pragma unroll
  for (int k = 0; k < 8; ++k) {
    a01 = hadd2(a01, v[k].x);
    a23 = hadd2(a23, v[k].y);
  }
  for (int eb = beg + 32; eb < end; eb += 16) {   // rare tail (P ~ 1e-4)
    int jx[4];
#pragma unroll
    for (int k = 0; k < 4; ++k) {
      int a = eb + k * 4 + sub;
      jx[k] = (a < end) ? csr[a] : npad;
    }
    uint2 w[4];
#pragma unroll
    for (int k = 0; k < 4; ++k)
      w[k] = *(const uint2*)&hin[(size_t)jx[k] * 64 + 4 * t];
#pragma unroll
    for (int k = 0; k < 4; ++k) {
      a01 = hadd2(a01, w[k].x);
      a23 = hadd2(a23, w[k].y);
    }
  }
}

__global__ __launch_bounds__(256) void k_hop64b(const unsigned short* __restrict__ hin,
    unsigned short* __restrict__ hout, const int* __restrict__ offs,
    const int* __restrict__ csr, int n, int nwaves) {
  const int lane = threadIdx.x & 63;
  const int sub = lane >> 4, t = lane & 15;
  for (int wid = blockIdx.x * 4 + (threadIdx.x >> 6); wid < n; wid += nwaves) {
    int beg = offs[wid], end = offs[wid + 1];
    unsigned int a01, a23;
    hop64_gather32(hin, csr, beg, end, sub, t, n, a01, a23);
    a01 = hadd2(a01, (unsigned int)__shfl_down((int)a01, 32, 64));
    a23 = hadd2(a23, (unsigned int)__shfl_down((int)a23, 32, 64));
    a01 = hadd2(a01, (unsigned int)__shfl_down((int)a01, 16, 64));
    a23 = hadd2(a23, (unsigned int)__shfl_down((int)a23, 16, 64));
    if (sub == 0) {
      uint2 sv = *(const uint2*)&hin[(size_t)wid * 64 + 4 * t];
      uint2 o;
      o.x = hadd2(a01, sv.x);
      o.y = hadd2(a23, sv.y);
      *(uint2*)&hout[(size_t)wid * 64 + 4 * t] = o;
    }
  }
}

// hop2: persistent grid-stride; stats accumulated in registers, one epilogue/block
__global__ __launch_bounds__(256) void k_hop64b_stats(const unsigned short* __restrict__ hin,
    unsigned short* __restrict__ hout, const int* __restrict__ offs,
    const int* __restrict__ csr, float* __restrict__ stats, int n, int nwaves) {
  const int lane = threadIdx.x & 63;
  const int sub = lane >> 4, t = lane & 15;
  float g1[4] = {}, g2[4] = {};
  for (int wid = blockIdx.x * 4 + (threadIdx.x >> 6); wid < n; wid += nwaves) {
    int beg = offs[wid], end = offs[wid + 1];
    unsigned int a01, a23;
    hop64_gather32(hin, csr, beg, end, sub, t, n, a01, a23);
    a01 = hadd2(a01, (unsigned int)__shfl_down((int)a01, 32, 64));
    a23 = hadd2(a23, (unsigned int)__shfl_down((int)a23, 32, 64));
    a01 = hadd2(a01, (unsigned int)__shfl_down((int)a01, 16, 64));
    a23 = hadd2(a23, (unsigned int)__shfl_down((int)a23, 16, 64));
    if (sub == 0) {
      uint2 sv = *(const uint2*)&hin[(size_t)wid * 64 + 4 * t];
      uint2 o;
      o.x = hadd2(a01, sv.x);
      o.y = hadd2(a23, sv.y);
      *(uint2*)&hout[(size_t)wid * 64 + 4 * t] = o;
      float2 p01 = h22f2(o.x), p23 = h22f2(o.y);
      g1[0] += p01.x; g2[0] += p01.x * p01.x;
      g1[1] += p01.y; g2[1] += p01.y * p01.y;
      g1[2] += p23.x; g2[2] += p23.x * p23.x;
      g1[3] += p23.y; g2[3] += p23.y * p23.y;
    }
  }
  __shared__ float l1[4][64];
  __shared__ float l2[4][64];
  const int w = threadIdx.x >> 6;
  if (sub == 0) {
    *(float4*)&l1[w][4 * t] = make_float4(g1[0], g1[1], g1[2], g1[3]);
    *(float4*)&l2[w][4 * t] = make_float4(g2[0], g2[1], g2[2], g2[3]);
  }
  __syncthreads();
  if (threadIdx.x < 64) {
    float t1 = l1[0][threadIdx.x] + l1[1][threadIdx.x] + l1[2][threadIdx.x] + l1[3][threadIdx.x];
    float t2 = l2[0][threadIdx.x] + l2[1][threadIdx.x] + l2[2][threadIdx.x] + l2[3][threadIdx.x];
    float* slot = stats + (size_t)(blockIdx.x & (NSLOT - 1)) * 128;
    atomicAdd(&slot[threadIdx.x], t1);
    atomicAdd(&slot[64 + threadIdx.x], t2);
  }
}

// ---------------------------------------------------------------- GEMM2 via MFMA with folded stats-finalize
__global__ __launch_bounds__(256) void k_gemm2(const unsigned short* __restrict__ A,
    const float* __restrict__ stats, const float* __restrict__ bn_w,
    const float* __restrict__ bn_b, const unsigned short* __restrict__ W2frag,
    unsigned short* __restrict__ Y, int n) {
  __shared__ float ab[128];
  if (threadIdx.x < 64) {
    int f = threadIdx.x;
    float s1 = 0.f, s2 = 0.f;
#pragma unroll 4
    for (int j = 0; j < NSLOT; ++j) {
      s1 += stats[(size_t)j * 128 + f];
      s2 += stats[(size_t)j * 128 + 64 + f];
    }
    float inv_n = 1.0f / (float)n;
    float mu = s1 * inv_n;
    float var = s2 * inv_n - mu * mu;
    float s = bn_w[f] * rsqrtf(var + 1e-5f);
    ab[f] = s;
    ab[64 + f] = bn_b[f] - mu * s;
  }
  __syncthreads();

  const int lane = threadIdx.x & 63;
  const int wv = threadIdx.x >> 6;
  const int r0 = blockIdx.x * 64 + wv * 16;
  const int brow = r0 + (lane & 15);
  const int browc = brow < n ? brow : n - 1;
  const int kbase = (lane >> 4) * 8;

  f32x4 acc = {};
#pragma unroll
  for (int kb = 0; kb < 2; ++kb) {
    int k0 = kb * 32 + kbase;
    uint4 a = *(const uint4*)&A[(size_t)browc * 64 + k0];
    unsigned int pk[4] = {a.x, a.y, a.z, a.w};
    half8 yf;
#pragma unroll
    for (int q = 0; q < 4; ++q) {
      float2 f2v = h22f2(pk[q]);
      float s0 = ab[k0 + 2 * q], sh0 = ab[64 + k0 + 2 * q];
      float s1 = ab[k0 + 2 * q + 1], sh1 = ab[64 + k0 + 2 * q + 1];
      float y0 = s0 * f2v.x + sh0;
      float y1 = s1 * f2v.y + sh1;
      y0 = y0 > 0.f ? SELU_LAMBDA * y0 : SELU_LAMBDA * SELU_ALPHA * expm1f(y0);
      y1 = y1 > 0.f ? SELU_LAMBDA * y1 : SELU_LAMBDA * SELU_ALPHA * expm1f(y1);
      yf[2 * q] = (_Float16)y0;
      yf[2 * q + 1] = (_Float16)y1;
    }
    half8 wf = *(const half8*)&W2frag[(size_t)(kb * 64 + lane) * 8];
    acc = __builtin_amdgcn_mfma_f32_16x16x32_f16(wf, yf, acc, 0, 0, 0);
  }
  const int orow = r0 + (lane & 15);
  if (orow < n) {
    uint2 o;
    o.x = f2h2(acc[0], acc[1]);
    o.y = f2h2(acc[2], acc[3]);
    *(uint2*)&Y[(size_t)orow * 16 + (lane >> 4) * 4] = o;
  }
}

// ---------------------------------------------------------------- hop at D=16 (fp16) + b2 + log_softmax, persistent grid-stride
// wave = one node per iteration; 16 subgroups x 4 lanes; lane loads uint2 (4 dims)
__global__ __launch_bounds__(256) void k_hop16(const unsigned short* __restrict__ Y,
    const float* __restrict__ b2, float* __restrict__ out,
    const int* __restrict__ offs, const int* __restrict__ csr, int n, int nwaves) {
  const int lane = threadIdx.x & 63;
  const int sub = lane >> 2, t = lane & 3;   // lane covers dims 4t..4t+3
  for (int wid = blockIdx.x * 4 + (threadIdx.x >> 6); wid < n; wid += nwaves) {
    int beg = offs[wid], end = offs[wid + 1];
    int i0, i1;
    {
      int a0i = beg + sub, a1i = beg + 16 + sub;
      i0 = (a0i < end) ? csr[a0i] : n;
      i1 = (a1i < end) ? csr[a1i] : n;
    }
    uint2 v0 = *(const uint2*)&Y[(size_t)i0 * 16 + 4 * t];
    uint2 v1 = *(const uint2*)&Y[(size_t)i1 * 16 + 4 * t];
    unsigned int a01 = hadd2(v0.x, v1.x);
    unsigned int a23 = hadd2(v0.y, v1.y);
    for (int eb = beg + 32; eb < end; eb += 16) {   // rare tail
      int a = eb + sub;
      int idx = (a < end) ? csr[a] : n;
      uint2 w = *(const uint2*)&Y[(size_t)idx * 16 + 4 * t];
      a01 = hadd2(a01, w.x);
      a23 = hadd2(a23, w.y);
    }
    a01 = hadd2(a01, (unsigned int)__shfl_down((int)a01, 32, 64));
    a23 = hadd2(a23, (unsigned int)__shfl_down((int)a23, 32, 64));
    a01 = hadd2(a01, (unsigned int)__shfl_down((int)a01, 16, 64));
    a23 = hadd2(a23, (unsigned int)__shfl_down((int)a23, 16, 64));
    a01 = hadd2(a01, (unsigned int)__shfl_down((int)a01, 8, 64));
    a23 = hadd2(a23, (unsigned int)__shfl_down((int)a23, 8, 64));
    a01 = hadd2(a01, (unsigned int)__shfl_down((int)a01, 4, 64));
    a23 = hadd2(a23, (unsigned int)__shfl_down((int)a23, 4, 64));
    if (sub == 0) {
      uint2 sv = *(const uint2*)&Y[(size_t)wid * 16 + 4 * t];
      float2 s01 = h22f2(sv.x), s23 = h22f2(sv.y);
      float2 p01 = h22f2(a01), p23 = h22f2(a23);
      float4 bb = *(const float4*)&b2[4 * t];
      float v0f = p01.x + s01.x + bb.x;
      float v1f = p01.y + s01.y + bb.y;
      float v2f = p23.x + s23.x + bb.z;
      float v3f = p23.y + s23.y + bb.w;
      float m = fmaxf(fmaxf(v0f, v1f), fmaxf(v2f, v3f));
      m = fmaxf(m, __shfl_xor(m, 1, 4));
      m = fmaxf(m, __shfl_xor(m, 2, 4));
      float s = expf(v0f - m) + expf(v1f - m) + expf(v2f - m) + expf(v3f - m);
      s += __shfl_xor(s, 1, 4);
      s += __shfl_xor(s, 2, 4);
      float ls = m + logf(s);
      *(float4*)&out[(size_t)wid * 16 + 4 * t] =
          make_float4(v0f - ls, v1f - ls, v2f - ls, v3f - ls);
    }
  }
}

// ---------------------------------------------------------------- launch
extern "C" void kernel_launch(void* const* d_in, const int* in_sizes, int n_in,
                              void* d_out, int out_size, void* d_ws, size_t ws_size,
                              hipStream_t stream) {
  const float* x   = (const float*)d_in[0];
  const int* esrc  = (const int*)d_in[1];
  const int* edst  = (const int*)d_in[2];
  const float* W1  = (const float*)d_in[3];
  // d_in[4] = b1: cancels exactly under batchnorm mean subtraction
  const float* bnw = (const float*)d_in[5];
  const float* bnb = (const float*)d_in[6];
  const float* W2  = (const float*)d_in[7];
  const float* b2  = (const float*)d_in[8];
  float* out = (float*)d_out;

  const int N = in_sizes[0] / 128;  // 100000
  const int E = in_sizes[1];        // 1600000
  const int NB = (N + BNODES - 1) >> BSHIFT;  // 196 buckets

  char* p = (char*)d_ws;
  auto alloc = [&](size_t bytes) {
    char* q = p;
    p += (bytes + 255) & ~(size_t)255;
    return q;
  };
  int* cursor  = (int*)alloc(256 * sizeof(int));
  int* binned  = (int*)alloc((size_t)NB * CAP * sizeof(int));
  int* offs    = (int*)alloc((size_t)(N + 4) * sizeof(int));
  int* csr     = (int*)alloc((size_t)E * sizeof(int));
  float* stats = (float*)alloc((size_t)NSLOT * 128 * sizeof(float));
  unsigned short* Wfrag  = (unsigned short*)alloc(1024 * 8 * sizeof(unsigned short));
  unsigned short* W2frag = (unsigned short*)alloc(128 * 8 * sizeof(unsigned short));
  unsigned short* h1 = (unsigned short*)alloc((size_t)(N + 1) * 64 * sizeof(unsigned short));
  unsigned short* h2 = (unsigned short*)alloc((size_t)(N + 1) * 64 * sizeof(unsigned short));
  unsigned short* h3 = (unsigned short*)alloc((size_t)N * 64 * sizeof(unsigned short));
  unsigned short* Yb = (unsigned short*)alloc((size_t)(N + 1) * 16 * sizeof(unsigned short));

  // setup: zero cursor/stats/pad rows + W1/W2 fragment prep (one dispatch)
  k_setup<<<32, 256, 0, stream>>>(cursor, stats, h1 + (size_t)N * 64,
                                  h2 + (size_t)N * 64, Yb + (size_t)N * 16,
                                  W1, Wfrag, W2, W2frag);

  // fused: edge binning + GEMM1 (independent work, co-resident blocks)
  const int nbin = (E + CHUNK - 1) / CHUNK;
  const int ng1 = (N + 63) / 64;
  k_bin_gemm1<<<nbin + ng1, 256, 0, stream>>>(esrc, edst, cursor, binned, E, nbin,
                                              x, Wfrag, h1, N);
  k_build<<<NB, 512, 0, stream>>>(binned, cursor, offs, csr, N, NB, E);

  // persistent hops at max occupancy (2048 blocks = 8/CU = 32 waves/CU)
  const int nwaves = HOPBLKS * 4;
  k_hop64b<<<HOPBLKS, 256, 0, stream>>>(h1, h2, offs, csr, N, nwaves);
  k_hop64b_stats<<<HOPBLKS, 256, 0, stream>>>(h2, h3, offs, csr, stats, N, nwaves);

  // GEMM2 (MFMA, folded stats-finalize + BN + SELU) then final hop at D=16
  k_gemm2<<<(N + 63) / 64, 256, 0, stream>>>(h3, stats, bnw, bnb, W2frag, Yb, N);
  k_hop16<<<HOPBLKS, 256, 0, stream>>>(Yb, b2, out, offs, csr, N, nwaves);
}